// Round 6
// baseline (361.237 us; speedup 1.0000x reference)
//
#include <hip/hip_runtime.h>
#include <math.h>

#define ROWS 18496          // bt*J*N = 64*17*17
#define SCALE 0.17677669529663687f  // 1/sqrt(32)

typedef unsigned short ushort_t;
typedef __attribute__((ext_vector_type(8))) short short8;
typedef __attribute__((ext_vector_type(4))) float f32x4;

__device__ __forceinline__ void fma4(float4& d, float s, const float4& v) {
    d.x = fmaf(s, v.x, d.x); d.y = fmaf(s, v.y, d.y);
    d.z = fmaf(s, v.z, d.z); d.w = fmaf(s, v.w, d.w);
}
__device__ __forceinline__ float dot4(const float4& a, const float4& b) {
    return a.x*b.x + a.y*b.y + a.z*b.z + a.w*b.w;
}

__device__ __forceinline__ ushort_t f2bf(float x) {
    union { float f; unsigned u; } v; v.f = x;
    unsigned r = v.u + 0x7fffu + ((v.u >> 16) & 1u);
    return (ushort_t)(r >> 16);
}
__device__ __forceinline__ float bf2f(ushort_t b) {
    union { unsigned u; float f; } v; v.u = ((unsigned)b) << 16; return v.f;
}

__device__ __forceinline__ void gl_lds16(const void* g, void* l) {
    __builtin_amdgcn_global_load_lds(
        (const __attribute__((address_space(1))) void*)g,
        (__attribute__((address_space(3))) void*)l, 16, 0, 0);
}

__device__ __forceinline__ void store_hilo(ushort_t* yhi, ushort_t* ylo,
                                           size_t off, const float4& a)
{
    ushort4 h, l;
    h.x = f2bf(a.x); l.x = f2bf(a.x - bf2f(h.x));
    h.y = f2bf(a.y); l.y = f2bf(a.y - bf2f(h.y));
    h.z = f2bf(a.z); l.z = f2bf(a.z - bf2f(h.z));
    h.w = f2bf(a.w); l.w = f2bf(a.w - bf2f(h.w));
    *(ushort4*)&yhi[off] = h;
    *(ushort4*)&ylo[off] = l;
}

// ---------------- merged conversion kernel ----------------------------
__global__ __launch_bounds__(256) void k_cvt_xw(
    const float4* __restrict__ x, ushort4* __restrict__ xhi, ushort4* __restrict__ xlo,
    const float* __restrict__ W, ushort_t* __restrict__ bh, ushort_t* __restrict__ bl)
{
    if (blockIdx.x < 4624) {
        int i = blockIdx.x * 256 + threadIdx.x;
        float4 v = x[i];
        ushort4 h, l;
        h.x = f2bf(v.x); l.x = f2bf(v.x - bf2f(h.x));
        h.y = f2bf(v.y); l.y = f2bf(v.y - bf2f(h.y));
        h.z = f2bf(v.z); l.z = f2bf(v.z - bf2f(h.z));
        h.w = f2bf(v.w); l.w = f2bf(v.w - bf2f(h.w));
        xhi[i] = h; xlo[i] = l;
    } else {
        int o = blockIdx.x - 4624;   // 0..1279
        int kk = threadIdx.x;        // 0..255
        int col = (o & 255) * 5 + (o >> 8);
        float v = W[(size_t)kk * 1280 + col];
        ushort_t hh = f2bf(v);
        bh[(size_t)o * 256 + kk] = hh;
        bl[(size_t)o * 256 + kk] = f2bf(v - bf2f(hh));
    }
}

// Wp (768x256 f32) -> transposed bf16 [n][k]
__global__ __launch_bounds__(256) void k_cvt_wp(
    const float* __restrict__ W, ushort_t* __restrict__ bh, ushort_t* __restrict__ bl)
{
    int n = blockIdx.x;          // 0..255
    for (int k = threadIdx.x; k < 768; k += 256) {
        float v = W[(size_t)k * 256 + n];
        ushort_t h = f2bf(v);
        bh[(size_t)n * 768 + k] = h;
        bl[(size_t)n * 768 + k] = f2bf(v - bf2f(h));
    }
}

// ---------------- split-bf16 MFMA GEMM --------------------------------
template<int BM, int BN, int K, int MODE>
__global__ __launch_bounds__(256) void k_gemm(
    const ushort_t* __restrict__ Ahi, const ushort_t* __restrict__ Alo,
    const ushort_t* __restrict__ Bhi, const ushort_t* __restrict__ Blo,
    const float* __restrict__ aux,
    float* __restrict__ out)
{
    constexpr int MT = BM / 32;
    constexpr int NT = BN / 32;
    __shared__ __attribute__((aligned(16))) ushort_t sAh[BM * 32];
    __shared__ __attribute__((aligned(16))) ushort_t sAl[BM * 32];
    __shared__ __attribute__((aligned(16))) ushort_t sBh[BN * 32];
    __shared__ __attribute__((aligned(16))) ushort_t sBl[BN * 32];

    const int t = threadIdx.x;
    const int lane = t & 63;
    const int ln = lane & 15, quad = lane >> 4;
    const int wave = t >> 6;
    const int wm = wave >> 1, wn = wave & 1;
    const int m0 = blockIdx.y * BM, n0 = blockIdx.x * BN;

    f32x4 acc[MT][NT];
#pragma unroll
    for (int i = 0; i < MT; ++i)
#pragma unroll
        for (int j = 0; j < NT; ++j) acc[i][j] = (f32x4){0.f, 0.f, 0.f, 0.f};

    for (int kb = 0; kb < K; kb += 32) {
        __syncthreads();
#pragma unroll
        for (int s = t; s < BM * 4; s += 256) {
            int row = s >> 2, kc = s & 3;
            int gr = m0 + row; if (gr > ROWS - 1) gr = ROWS - 1;
            size_t gb = ((size_t)gr * K + kb) * 2 + kc * 16;
            int lb = (s & ~63) * 16;
            gl_lds16((const char*)Ahi + gb, (char*)sAh + lb);
            gl_lds16((const char*)Alo + gb, (char*)sAl + lb);
        }
#pragma unroll
        for (int s = t; s < BN * 4; s += 256) {
            int row = s >> 2, kc = s & 3;
            size_t gb = ((size_t)(n0 + row) * K + kb) * 2 + kc * 16;
            int lb = (s & ~63) * 16;
            gl_lds16((const char*)Bhi + gb, (char*)sBh + lb);
            gl_lds16((const char*)Blo + gb, (char*)sBl + lb);
        }
        __syncthreads();

        short8 ah[MT], al[MT], bh[NT], bl[NT];
#pragma unroll
        for (int i = 0; i < MT; ++i) {
            int off = (wm * (BM / 2) + i * 16 + ln) * 32 + quad * 8;
            ah[i] = *(const short8*)&sAh[off];
            al[i] = *(const short8*)&sAl[off];
        }
#pragma unroll
        for (int j = 0; j < NT; ++j) {
            int off = (wn * (BN / 2) + j * 16 + ln) * 32 + quad * 8;
            bh[j] = *(const short8*)&sBh[off];
            bl[j] = *(const short8*)&sBl[off];
        }
#pragma unroll
        for (int i = 0; i < MT; ++i)
#pragma unroll
            for (int j = 0; j < NT; ++j) {
                acc[i][j] = __builtin_amdgcn_mfma_f32_16x16x32_bf16(ah[i], bh[j], acc[i][j], 0, 0, 0);
                acc[i][j] = __builtin_amdgcn_mfma_f32_16x16x32_bf16(ah[i], bl[j], acc[i][j], 0, 0, 0);
                acc[i][j] = __builtin_amdgcn_mfma_f32_16x16x32_bf16(al[i], bh[j], acc[i][j], 0, 0, 0);
            }
    }

#pragma unroll
    for (int i = 0; i < MT; ++i) {
#pragma unroll
        for (int r = 0; r < 4; ++r) {
            int gm = m0 + wm * (BM / 2) + i * 16 + quad * 4 + r;
            if (gm >= ROWS) continue;
            if (MODE == 0) {
                int jn = gm % 289;
                const float* Mrow = &aux[(size_t)jn * 256];
#pragma unroll
                for (int j = 0; j < NT; ++j) {
                    int gn = n0 + wn * (BN / 2) + j * 16 + ln;
                    out[(size_t)gm * 1280 + gn] = acc[i][j][r] * Mrow[gn & 255];
                }
            } else {
#pragma unroll
                for (int j = 0; j < NT; ++j) {
                    int gn = n0 + wn * (BN / 2) + j * 16 + ln;
                    out[(size_t)gm * 256 + gn] = acc[i][j][r] + aux[gn];
                }
            }
        }
    }
}

// ---------------- fused attention v3: reg-prefetch pipeline -------------
// Block per (b,h), 320 threads, 64.7 KB LDS (2 blocks/CU). 8 staging rounds;
// each round's global loads are issued into registers BEFORE the previous
// round's compute, so HBM latency hides behind compute instead of sitting
// between barriers. Consumers hold ch0 accumulators and store ch0+ch1
// together (full 64B line coverage).
__device__ __forceinline__ void stage_load(const float* __restrict__ qkv5,
    size_t rowbase, int colbase, int t, float4* pf)
{
#pragma unroll
    for (int r = 0; r < 4; ++r) {
        int idx = t + r * 320;
        if (idx < 1156) {
            int p = idx >> 2, c = idx & 3;
            pf[r] = *(const float4*)&qkv5[(rowbase + p) * 1280 + colbase + c * 4];
        }
    }
}
__device__ __forceinline__ void stage_store(float* buf, int t, const float4* pf)
{
#pragma unroll
    for (int r = 0; r < 4; ++r) {
        int idx = t + r * 320;
        if (idx < 1156) {
            int p = idx >> 2, c = idx & 3;
            *(float4*)&buf[p * 20 + c * 4] = pf[r];
        }
    }
}

__device__ __forceinline__ void score_half(
    float* accS, float* accV, const float4* q, const float* buf, int a, int bb)
{
#pragma unroll
    for (int kk = 0; kk < 17; ++kk) {
        const float4* r = (const float4*)&buf[(kk * 17 + bb) * 20];
        accS[kk] += dot4(q[0], r[0]) + dot4(q[1], r[1]) + dot4(q[2], r[2]) + dot4(q[3], r[3]);
    }
#pragma unroll
    for (int mm = 0; mm < 17; ++mm) {
        const float4* r = (const float4*)&buf[(a * 17 + mm) * 20];
        accV[mm] += dot4(q[0], r[0]) + dot4(q[1], r[1]) + dot4(q[2], r[2]) + dot4(q[3], r[3]);
    }
}

// x_vs-style round: out[ti][row] for 2 tasks x 2 rows (normalized)
__device__ __forceinline__ void p4_round(
    const float* aS, const float* ebS, const float* buf, int t, float4 out[2][2])
{
#pragma unroll
    for (int ti = 0; ti < 2; ++ti) {
        int u = t + ti * 320;
        if (u >= 612) break;
        int cc = (u & 3) * 4, rest = u >> 2;
        int n = rest % 17, jp = rest / 17;
        int j0 = jp * 2;
        int j1 = (j0 + 1 > 16) ? 16 : j0 + 1;
        float w0[17], w1[17];
        float s0 = 0.f, s1 = 0.f;
        const float* as0 = &aS[n * 289 + j0 * 17];
        const float* as1 = &aS[n * 289 + j1 * 17];
        const float* e0 = &ebS[j0 * 17];
        const float* e1 = &ebS[j1 * 17];
#pragma unroll
        for (int kk = 0; kk < 17; ++kk) {
            w0[kk] = as0[kk] * e0[kk]; s0 += w0[kk];
            w1[kk] = as1[kk] * e1[kk]; s1 += w1[kk];
        }
        float i0 = 1.f / s0, i1 = 1.f / s1;
        float4 a0 = {0,0,0,0}, a1 = {0,0,0,0};
        for (int kk = 0; kk < 17; ++kk) {
            float4 v = *(const float4*)&buf[(kk * 17 + n) * 20 + cc];
            fma4(a0, w0[kk], v);
            fma4(a1, w1[kk], v);
        }
        a0.x *= i0; a0.y *= i0; a0.z *= i0; a0.w *= i0;
        a1.x *= i1; a1.y *= i1; a1.z *= i1; a1.w *= i1;
        out[ti][0] = a0; out[ti][1] = a1;
    }
}

// x_vv-style round
__device__ __forceinline__ void p5_round(
    const float* aV, const float* ebV, const float* buf, int t, float4 out[2][2])
{
#pragma unroll
    for (int ti = 0; ti < 2; ++ti) {
        int u = t + ti * 320;
        if (u >= 612) break;
        int cc = (u & 3) * 4, rest = u >> 2;
        int j = rest % 17, np = rest / 17;
        int n0 = np * 2;
        int n1 = (n0 + 1 > 16) ? 16 : n0 + 1;
        float w0[17], w1[17];
        float s0 = 0.f, s1 = 0.f;
        const float* av0 = &aV[j * 289 + n0 * 17];
        const float* av1 = &aV[j * 289 + n1 * 17];
        const float* e0 = &ebV[n0 * 17];
        const float* e1 = &ebV[n1 * 17];
#pragma unroll
        for (int mm = 0; mm < 17; ++mm) {
            w0[mm] = av0[mm] * e0[mm]; s0 += w0[mm];
            w1[mm] = av1[mm] * e1[mm]; s1 += w1[mm];
        }
        float i0 = 1.f / s0, i1 = 1.f / s1;
        float4 a0 = {0,0,0,0}, a1 = {0,0,0,0};
        for (int mm = 0; mm < 17; ++mm) {
            float4 v = *(const float4*)&buf[(j * 17 + mm) * 20 + cc];
            fma4(a0, w0[mm], v);
            fma4(a1, w1[mm], v);
        }
        a0.x *= i0; a0.y *= i0; a0.z *= i0; a0.w *= i0;
        a1.x *= i1; a1.y *= i1; a1.z *= i1; a1.w *= i1;
        out[ti][0] = a0; out[ti][1] = a1;
    }
}

__global__ __launch_bounds__(320) void k_att(
    const float* __restrict__ qkv5,
    const float* __restrict__ A_s, const float* __restrict__ A_v,
    const float* __restrict__ adjS, const float* __restrict__ adjV,
    ushort_t* __restrict__ yhi, ushort_t* __restrict__ ylo)
{
    __shared__ __attribute__((aligned(16))) float sm[16184];
    float* aS  = sm;            // 4913  [n][j][k]
    float* aV  = sm + 4913;     // 4913  [j][n][m]
    float* ebS = sm + 9826;     // 289
    float* ebV = sm + 10115;    // 289
    float* buf = sm + 10404;    // 289*20

    const int t  = threadIdx.x;
    const int bh = blockIdx.x;
    const int b  = bh >> 3, h = bh & 7;
    const size_t rowbase = (size_t)b * 289;
    const int colq = h * 32;

    // q preload (both channel halves) into registers
    float4 qreg[8];
    if (t < 289) {
        const float* qp = &qkv5[(rowbase + t) * 1280 + colq];
#pragma unroll
        for (int c = 0; c < 8; ++c) qreg[c] = *(const float4*)&qp[c * 4];
    }

    float4 pf[4];
    stage_load(qkv5, rowbase, 256 + colq, t, pf);            // k-tile ch0

    // P0: exp of symmetrized biases
    for (int idx = t; idx < 578; idx += 320) {
        int f = idx / 289, rem = idx % 289;
        int jj = rem / 17, kk = rem % 17;
        float bias;
        if (f == 0)
            bias = 0.5f * ((A_s[jj*17+kk] + adjS[jj*17+kk]) + (A_s[kk*17+jj] + adjS[kk*17+jj]));
        else
            bias = 0.5f * ((A_v[jj*17+kk] + adjV[jj*17+kk]) + (A_v[kk*17+jj] + adjV[kk*17+jj]));
        (f ? ebV : ebS)[rem] = expf(bias);
    }

    stage_store(buf, t, pf);
    stage_load(qkv5, rowbase, 256 + colq + 16, t, pf);       // k-tile ch1
    __syncthreads();

    // ---- scores ch0 ----
    float accS[17], accV[17];
#pragma unroll
    for (int i = 0; i < 17; ++i) { accS[i] = 0.f; accV[i] = 0.f; }
    const int a = t / 17, bb = t % 17;
    if (t < 289) score_half(accS, accV, &qreg[0], buf, a, bb);
    __syncthreads();

    stage_store(buf, t, pf);
    stage_load(qkv5, rowbase, 1024 + colq, t, pf);           // vsv ch0
    __syncthreads();

    // ---- scores ch1 + write raw scores ----
    if (t < 289) {
        score_half(accS, accV, &qreg[4], buf, a, bb);
#pragma unroll
        for (int kk = 0; kk < 17; ++kk) aS[bb * 289 + a * 17 + kk] = accS[kk] * SCALE;
#pragma unroll
        for (int mm = 0; mm < 17; ++mm) aV[a * 289 + bb * 17 + mm] = accV[mm] * SCALE;
    }
    __syncthreads();

    // ---- softmax (in-place, unbiased) on all 578 rows ----
    for (int idx = t; idx < 578; idx += 320) {
        float* row = (idx < 289) ? &aS[idx * 17] : &aV[(idx - 289) * 17];
        float v[17];
#pragma unroll
        for (int kk = 0; kk < 17; ++kk) v[kk] = row[kk];
        float mx = v[0];
#pragma unroll
        for (int kk = 1; kk < 17; ++kk) mx = fmaxf(mx, v[kk]);
        float sum = 0.f;
#pragma unroll
        for (int kk = 0; kk < 17; ++kk) { v[kk] = expf(v[kk] - mx); sum += v[kk]; }
        float inv = 1.f / sum;
#pragma unroll
        for (int kk = 0; kk < 17; ++kk) row[kk] = v[kk] * inv;
    }
    __syncthreads();

    stage_store(buf, t, pf);                                 // buf = vsv ch0
    stage_load(qkv5, rowbase, 1024 + colq + 16, t, pf);      // vsv ch1
    __syncthreads();

    // ---- P3: x_vsv, 4 points/thread, ch0 then ch1 (acc held) ----
    const int c4 = (t & 3) * 4;
    const int pb = (t >> 2) * 4;
    const int nv = (t < 292) ? ((289 - pb < 4) ? (289 - pb) : 4) : 0;
    int jj3[4], nn3[4];
    float eV[4][17];
    float4 acc3[2][4];
    if (t < 292) {
#pragma unroll
        for (int g = 0; g < 4; ++g) {
            int p = pb + g; if (p > 288) p = 288;
            jj3[g] = p / 17; nn3[g] = p % 17;
            const float* src = &aV[jj3[g] * 289 + nn3[g] * 17];
#pragma unroll
            for (int m = 0; m < 17; ++m) eV[g][m] = src[m];
        }
#pragma unroll
        for (int g = 0; g < 4; ++g) acc3[0][g] = (float4){0,0,0,0};
        for (int kk = 0; kk < 17; ++kk) {
            float4 tg[4];
#pragma unroll
            for (int g = 0; g < 4; ++g) tg[g] = (float4){0,0,0,0};
#pragma unroll
            for (int m = 0; m < 17; ++m) {
                float4 v = *(const float4*)&buf[(kk * 17 + m) * 20 + c4];
#pragma unroll
                for (int g = 0; g < 4; ++g) fma4(tg[g], eV[g][m], v);
            }
#pragma unroll
            for (int g = 0; g < 4; ++g)
                fma4(acc3[0][g], aS[nn3[g] * 289 + jj3[g] * 17 + kk], tg[g]);
        }
    }
    __syncthreads();

    stage_store(buf, t, pf);                                 // buf = vsv ch1
    stage_load(qkv5, rowbase, 512 + colq, t, pf);            // vs ch0
    __syncthreads();

    if (t < 292) {
#pragma unroll
        for (int g = 0; g < 4; ++g) acc3[1][g] = (float4){0,0,0,0};
        for (int kk = 0; kk < 17; ++kk) {
            float4 tg[4];
#pragma unroll
            for (int g = 0; g < 4; ++g) tg[g] = (float4){0,0,0,0};
#pragma unroll
            for (int m = 0; m < 17; ++m) {
                float4 v = *(const float4*)&buf[(kk * 17 + m) * 20 + c4];
#pragma unroll
                for (int g = 0; g < 4; ++g) fma4(tg[g], eV[g][m], v);
            }
#pragma unroll
            for (int g = 0; g < 4; ++g)
                fma4(acc3[1][g], aS[nn3[g] * 289 + jj3[g] * 17 + kk], tg[g]);
        }
        for (int g = 0; g < nv; ++g) {
            size_t base = (rowbase + pb + g) * 768 + colq + c4;
            store_hilo(yhi, ylo, base, acc3[0][g]);
            store_hilo(yhi, ylo, base + 16, acc3[1][g]);
        }
    }
    __syncthreads();

    stage_store(buf, t, pf);                                 // buf = vs ch0
    stage_load(qkv5, rowbase, 512 + colq + 16, t, pf);       // vs ch1
    __syncthreads();

    // ---- P4: x_vs, ch0 (held) then ch1 + combined store ----
    float4 hold[2][2][2];   // [ch][ti][row]
    p4_round(aS, ebS, buf, t, hold[0]);
    __syncthreads();

    stage_store(buf, t, pf);                                 // buf = vs ch1
    stage_load(qkv5, rowbase, 768 + colq, t, pf);            // vv ch0
    __syncthreads();

    p4_round(aS, ebS, buf, t, hold[1]);
#pragma unroll
    for (int ti = 0; ti < 2; ++ti) {
        int u = t + ti * 320;
        if (u >= 612) break;
        int cc = (u & 3) * 4, rest = u >> 2;
        int n = rest % 17, jp = rest / 17;
        int j0 = jp * 2;
        size_t base0 = (rowbase + j0 * 17 + n) * 768 + 256 + colq + cc;
        store_hilo(yhi, ylo, base0, hold[0][ti][0]);
        store_hilo(yhi, ylo, base0 + 16, hold[1][ti][0]);
        if (j0 != 16) {
            size_t base1 = (rowbase + (j0 + 1) * 17 + n) * 768 + 256 + colq + cc;
            store_hilo(yhi, ylo, base1, hold[0][ti][1]);
            store_hilo(yhi, ylo, base1 + 16, hold[1][ti][1]);
        }
    }
    __syncthreads();

    stage_store(buf, t, pf);                                 // buf = vv ch0
    stage_load(qkv5, rowbase, 768 + colq + 16, t, pf);       // vv ch1
    __syncthreads();

    // ---- P5: x_vv, ch0 (held) then ch1 + combined store ----
    p5_round(aV, ebV, buf, t, hold[0]);
    __syncthreads();

    stage_store(buf, t, pf);                                 // buf = vv ch1
    __syncthreads();

    p5_round(aV, ebV, buf, t, hold[1]);
#pragma unroll
    for (int ti = 0; ti < 2; ++ti) {
        int u = t + ti * 320;
        if (u >= 612) break;
        int cc = (u & 3) * 4, rest = u >> 2;
        int j = rest % 17, np = rest / 17;
        int n0 = np * 2;
        size_t base0 = (rowbase + j * 17 + n0) * 768 + 512 + colq + cc;
        store_hilo(yhi, ylo, base0, hold[0][ti][0]);
        store_hilo(yhi, ylo, base0 + 16, hold[1][ti][0]);
        if (n0 != 16) {
            size_t base1 = (rowbase + j * 17 + n0 + 1) * 768 + 512 + colq + cc;
            store_hilo(yhi, ylo, base1, hold[0][ti][1]);
            store_hilo(yhi, ylo, base1 + 16, hold[1][ti][1]);
        }
    }
}

extern "C" void kernel_launch(void* const* d_in, const int* in_sizes, int n_in,
                              void* d_out, int out_size, void* d_ws, size_t ws_size,
                              hipStream_t stream)
{
    const float* x    = (const float*)d_in[0];
    const float* A_s  = (const float*)d_in[1];
    const float* A_v  = (const float*)d_in[2];
    const float* Wqkv = (const float*)d_in[3];
    const float* Wp   = (const float*)d_in[4];
    const float* bp   = (const float*)d_in[5];
    const float* M    = (const float*)d_in[6];
    const float* adjS = (const float*)d_in[7];
    const float* adjV = (const float*)d_in[8];
    float* out = (float*)d_out;

    char* w = (char*)d_ws;
    float*    qkv5  = (float*)w;                          // 95 MB, dead after k_att
    ushort_t* wph   = (ushort_t*)w;                       // written after k_att
    ushort_t* wpl   = (ushort_t*)(w + 393216);
    char* R = w + 134946816;
    ushort_t* xhi = (ushort_t*)R;
    ushort_t* xlo = (ushort_t*)(R + 9469952);
    ushort_t* wqh = (ushort_t*)(R + 18939904);
    ushort_t* wql = (ushort_t*)(R + 19595264);
    ushort_t* yhi = (ushort_t*)R;                         // alias (after qkv gemm done)
    ushort_t* ylo = (ushort_t*)(R + 28422144);

    k_cvt_xw<<<dim3(5904), 256, 0, stream>>>((const float4*)x, (ushort4*)xhi, (ushort4*)xlo,
                                             Wqkv, wqh, wql);
    k_gemm<128, 128, 256, 0><<<dim3(10, 145), 256, 0, stream>>>(xhi, xlo, wqh, wql, M, qkv5);
    k_att<<<dim3(512), 320, 0, stream>>>(qkv5, A_s, A_v, adjS, adjV, yhi, ylo);
    k_cvt_wp<<<dim3(256), 256, 0, stream>>>(Wp, wph, wpl);
    k_gemm<128, 64, 768, 1><<<dim3(4, 145), 256, 0, stream>>>(yhi, ylo, wph, wpl, bp, out);
}

// Round 8
// 345.485 us; speedup vs baseline: 1.0456x; 1.0456x over previous
//
#include <hip/hip_runtime.h>
#include <math.h>

#define ROWS 18496          // bt*J*N = 64*17*17
#define SCALE 0.17677669529663687f  // 1/sqrt(32)

typedef unsigned short ushort_t;
typedef __attribute__((ext_vector_type(8))) short short8;
typedef __attribute__((ext_vector_type(8))) unsigned short us8;
typedef __attribute__((ext_vector_type(4))) float f32x4;

__device__ __forceinline__ void fma4(float4& d, float s, const float4& v) {
    d.x = fmaf(s, v.x, d.x); d.y = fmaf(s, v.y, d.y);
    d.z = fmaf(s, v.z, d.z); d.w = fmaf(s, v.w, d.w);
}
__device__ __forceinline__ float dot4(const float4& a, const float4& b) {
    return a.x*b.x + a.y*b.y + a.z*b.z + a.w*b.w;
}

__device__ __forceinline__ ushort_t f2bf(float x) {
    union { float f; unsigned u; } v; v.f = x;
    unsigned r = v.u + 0x7fffu + ((v.u >> 16) & 1u);
    return (ushort_t)(r >> 16);
}
__device__ __forceinline__ float bf2f(ushort_t b) {
    union { unsigned u; float f; } v; v.u = ((unsigned)b) << 16; return v.f;
}

__device__ __forceinline__ void gl_lds16(const void* g, void* l) {
    __builtin_amdgcn_global_load_lds(
        (const __attribute__((address_space(1))) void*)g,
        (__attribute__((address_space(3))) void*)l, 16, 0, 0);
}

// 8 contiguous cols (a0 = cols 0..3, a1 = cols 4..7) -> one 16B store per array.
__device__ __forceinline__ void store_hilo8(ushort_t* __restrict__ yhi,
                                            ushort_t* __restrict__ ylo,
                                            size_t off, const float4& a0, const float4& a1)
{
    us8 h, l;
    h[0] = f2bf(a0.x); l[0] = f2bf(a0.x - bf2f(h[0]));
    h[1] = f2bf(a0.y); l[1] = f2bf(a0.y - bf2f(h[1]));
    h[2] = f2bf(a0.z); l[2] = f2bf(a0.z - bf2f(h[2]));
    h[3] = f2bf(a0.w); l[3] = f2bf(a0.w - bf2f(h[3]));
    h[4] = f2bf(a1.x); l[4] = f2bf(a1.x - bf2f(h[4]));
    h[5] = f2bf(a1.y); l[5] = f2bf(a1.y - bf2f(h[5]));
    h[6] = f2bf(a1.z); l[6] = f2bf(a1.z - bf2f(h[6]));
    h[7] = f2bf(a1.w); l[7] = f2bf(a1.w - bf2f(h[7]));
    *(us8*)&yhi[off] = h;
    *(us8*)&ylo[off] = l;
}

// ---------------- merged conversion kernel ----------------------------
__global__ __launch_bounds__(256) void k_cvt_xw(
    const float4* __restrict__ x, ushort4* __restrict__ xhi, ushort4* __restrict__ xlo,
    const float* __restrict__ W, ushort_t* __restrict__ bh, ushort_t* __restrict__ bl)
{
    if (blockIdx.x < 4624) {
        int i = blockIdx.x * 256 + threadIdx.x;
        float4 v = x[i];
        ushort4 h, l;
        h.x = f2bf(v.x); l.x = f2bf(v.x - bf2f(h.x));
        h.y = f2bf(v.y); l.y = f2bf(v.y - bf2f(h.y));
        h.z = f2bf(v.z); l.z = f2bf(v.z - bf2f(h.z));
        h.w = f2bf(v.w); l.w = f2bf(v.w - bf2f(h.w));
        xhi[i] = h; xlo[i] = l;
    } else {
        int o = blockIdx.x - 4624;   // 0..1279
        int kk = threadIdx.x;        // 0..255
        int col = (o & 255) * 5 + (o >> 8);
        float v = W[(size_t)kk * 1280 + col];
        ushort_t hh = f2bf(v);
        bh[(size_t)o * 256 + kk] = hh;
        bl[(size_t)o * 256 + kk] = f2bf(v - bf2f(hh));
    }
}

// Wp (768x256 f32) -> transposed bf16 [n][k]
__global__ __launch_bounds__(256) void k_cvt_wp(
    const float* __restrict__ W, ushort_t* __restrict__ bh, ushort_t* __restrict__ bl)
{
    int n = blockIdx.x;          // 0..255
    for (int k = threadIdx.x; k < 768; k += 256) {
        float v = W[(size_t)k * 256 + n];
        ushort_t h = f2bf(v);
        bh[(size_t)n * 768 + k] = h;
        bl[(size_t)n * 768 + k] = f2bf(v - bf2f(h));
    }
}

// ---------------- split-bf16 MFMA GEMM --------------------------------
template<int BM, int BN, int K, int MODE>
__global__ __launch_bounds__(256) void k_gemm(
    const ushort_t* __restrict__ Ahi, const ushort_t* __restrict__ Alo,
    const ushort_t* __restrict__ Bhi, const ushort_t* __restrict__ Blo,
    const float* __restrict__ aux,
    float* __restrict__ out)
{
    constexpr int MT = BM / 32;
    constexpr int NT = BN / 32;
    __shared__ __attribute__((aligned(16))) ushort_t sAh[BM * 32];
    __shared__ __attribute__((aligned(16))) ushort_t sAl[BM * 32];
    __shared__ __attribute__((aligned(16))) ushort_t sBh[BN * 32];
    __shared__ __attribute__((aligned(16))) ushort_t sBl[BN * 32];

    const int t = threadIdx.x;
    const int lane = t & 63;
    const int ln = lane & 15, quad = lane >> 4;
    const int wave = t >> 6;
    const int wm = wave >> 1, wn = wave & 1;
    const int m0 = blockIdx.y * BM, n0 = blockIdx.x * BN;

    f32x4 acc[MT][NT];
#pragma unroll
    for (int i = 0; i < MT; ++i)
#pragma unroll
        for (int j = 0; j < NT; ++j) acc[i][j] = (f32x4){0.f, 0.f, 0.f, 0.f};

    for (int kb = 0; kb < K; kb += 32) {
        __syncthreads();
#pragma unroll
        for (int s = t; s < BM * 4; s += 256) {
            int row = s >> 2, kc = s & 3;
            int gr = m0 + row; if (gr > ROWS - 1) gr = ROWS - 1;
            size_t gb = ((size_t)gr * K + kb) * 2 + kc * 16;
            int lb = (s & ~63) * 16;
            gl_lds16((const char*)Ahi + gb, (char*)sAh + lb);
            gl_lds16((const char*)Alo + gb, (char*)sAl + lb);
        }
#pragma unroll
        for (int s = t; s < BN * 4; s += 256) {
            int row = s >> 2, kc = s & 3;
            size_t gb = ((size_t)(n0 + row) * K + kb) * 2 + kc * 16;
            int lb = (s & ~63) * 16;
            gl_lds16((const char*)Bhi + gb, (char*)sBh + lb);
            gl_lds16((const char*)Blo + gb, (char*)sBl + lb);
        }
        __syncthreads();

        short8 ah[MT], al[MT], bh[NT], bl[NT];
#pragma unroll
        for (int i = 0; i < MT; ++i) {
            int off = (wm * (BM / 2) + i * 16 + ln) * 32 + quad * 8;
            ah[i] = *(const short8*)&sAh[off];
            al[i] = *(const short8*)&sAl[off];
        }
#pragma unroll
        for (int j = 0; j < NT; ++j) {
            int off = (wn * (BN / 2) + j * 16 + ln) * 32 + quad * 8;
            bh[j] = *(const short8*)&sBh[off];
            bl[j] = *(const short8*)&sBl[off];
        }
#pragma unroll
        for (int i = 0; i < MT; ++i)
#pragma unroll
            for (int j = 0; j < NT; ++j) {
                acc[i][j] = __builtin_amdgcn_mfma_f32_16x16x32_bf16(ah[i], bh[j], acc[i][j], 0, 0, 0);
                acc[i][j] = __builtin_amdgcn_mfma_f32_16x16x32_bf16(ah[i], bl[j], acc[i][j], 0, 0, 0);
                acc[i][j] = __builtin_amdgcn_mfma_f32_16x16x32_bf16(al[i], bh[j], acc[i][j], 0, 0, 0);
            }
    }

#pragma unroll
    for (int i = 0; i < MT; ++i) {
#pragma unroll
        for (int r = 0; r < 4; ++r) {
            int gm = m0 + wm * (BM / 2) + i * 16 + quad * 4 + r;
            if (gm >= ROWS) continue;
            if (MODE == 0) {
                int jn = gm % 289;
                const float* Mrow = &aux[(size_t)jn * 256];
#pragma unroll
                for (int j = 0; j < NT; ++j) {
                    int gn = n0 + wn * (BN / 2) + j * 16 + ln;
                    out[(size_t)gm * 1280 + gn] = acc[i][j][r] * Mrow[gn & 255];
                }
            } else {
#pragma unroll
                for (int j = 0; j < NT; ++j) {
                    int gn = n0 + wn * (BN / 2) + j * 16 + ln;
                    out[(size_t)gm * 256 + gn] = acc[i][j][r] + aux[gn];
                }
            }
        }
    }
}

// ---------------- fused attention v4 -----------------------------------
// Block per (b,h), 320 threads, reg-prefetch pipeline (as R6), BUT channel
// phases now cover interleaved col-quads: ch0 = quads {0,2,4,6}, ch1 =
// {1,3,5,7}. A thread's (ch0,ch1) accumulator pair = 8 CONTIGUOUS cols ->
// single 16B store per array per point -> 4 lanes fill a 64B line in ONE
// instruction (no partial-sector write-allocate).
__device__ __forceinline__ void stage_load(const float* __restrict__ qkv5,
    size_t rowbase, int colbase, int t, float4* pf)
{
#pragma unroll
    for (int r = 0; r < 4; ++r) {
        int idx = t + r * 320;
        if (idx < 1156) {
            int p = idx >> 2, c = idx & 3;
            pf[r] = *(const float4*)&qkv5[(rowbase + p) * 1280 + colbase + c * 8];
        }
    }
}
__device__ __forceinline__ void stage_store(float* buf, int t, const float4* pf)
{
#pragma unroll
    for (int r = 0; r < 4; ++r) {
        int idx = t + r * 320;
        if (idx < 1156) {
            int p = idx >> 2, c = idx & 3;
            *(float4*)&buf[p * 20 + c * 4] = pf[r];
        }
    }
}

// q chunks must be selected to match the staged col-quads: slot c <-> quad 2c+ch.
__device__ __forceinline__ void score_half(
    float* accS, float* accV, const float4* qsel, const float* buf, int a, int bb)
{
#pragma unroll
    for (int kk = 0; kk < 17; ++kk) {
        const float4* r = (const float4*)&buf[(kk * 17 + bb) * 20];
        accS[kk] += dot4(qsel[0], r[0]) + dot4(qsel[1], r[1]) + dot4(qsel[2], r[2]) + dot4(qsel[3], r[3]);
    }
#pragma unroll
    for (int mm = 0; mm < 17; ++mm) {
        const float4* r = (const float4*)&buf[(a * 17 + mm) * 20];
        accV[mm] += dot4(qsel[0], r[0]) + dot4(qsel[1], r[1]) + dot4(qsel[2], r[2]) + dot4(qsel[3], r[3]);
    }
}

// x_vs-style round: out[ti][row] for 2 tasks x 2 rows (normalized)
__device__ __forceinline__ void p4_round(
    const float* aS, const float* ebS, const float* buf, int t, float4 out[2][2])
{
#pragma unroll
    for (int ti = 0; ti < 2; ++ti) {
        int u = t + ti * 320;
        if (u >= 612) break;
        int cc = (u & 3) * 4, rest = u >> 2;
        int n = rest % 17, jp = rest / 17;
        int j0 = jp * 2;
        int j1 = (j0 + 1 > 16) ? 16 : j0 + 1;
        float w0[17], w1[17];
        float s0 = 0.f, s1 = 0.f;
        const float* as0 = &aS[n * 289 + j0 * 17];
        const float* as1 = &aS[n * 289 + j1 * 17];
        const float* e0 = &ebS[j0 * 17];
        const float* e1 = &ebS[j1 * 17];
#pragma unroll
        for (int kk = 0; kk < 17; ++kk) {
            w0[kk] = as0[kk] * e0[kk]; s0 += w0[kk];
            w1[kk] = as1[kk] * e1[kk]; s1 += w1[kk];
        }
        float i0 = 1.f / s0, i1 = 1.f / s1;
        float4 a0 = {0,0,0,0}, a1 = {0,0,0,0};
        for (int kk = 0; kk < 17; ++kk) {
            float4 v = *(const float4*)&buf[(kk * 17 + n) * 20 + cc];
            fma4(a0, w0[kk], v);
            fma4(a1, w1[kk], v);
        }
        a0.x *= i0; a0.y *= i0; a0.z *= i0; a0.w *= i0;
        a1.x *= i1; a1.y *= i1; a1.z *= i1; a1.w *= i1;
        out[ti][0] = a0; out[ti][1] = a1;
    }
}

// x_vv-style round
__device__ __forceinline__ void p5_round(
    const float* aV, const float* ebV, const float* buf, int t, float4 out[2][2])
{
#pragma unroll
    for (int ti = 0; ti < 2; ++ti) {
        int u = t + ti * 320;
        if (u >= 612) break;
        int cc = (u & 3) * 4, rest = u >> 2;
        int j = rest % 17, np = rest / 17;
        int n0 = np * 2;
        int n1 = (n0 + 1 > 16) ? 16 : n0 + 1;
        float w0[17], w1[17];
        float s0 = 0.f, s1 = 0.f;
        const float* av0 = &aV[j * 289 + n0 * 17];
        const float* av1 = &aV[j * 289 + n1 * 17];
        const float* e0 = &ebV[n0 * 17];
        const float* e1 = &ebV[n1 * 17];
#pragma unroll
        for (int mm = 0; mm < 17; ++mm) {
            w0[mm] = av0[mm] * e0[mm]; s0 += w0[mm];
            w1[mm] = av1[mm] * e1[mm]; s1 += w1[mm];
        }
        float i0 = 1.f / s0, i1 = 1.f / s1;
        float4 a0 = {0,0,0,0}, a1 = {0,0,0,0};
        for (int mm = 0; mm < 17; ++mm) {
            float4 v = *(const float4*)&buf[(j * 17 + mm) * 20 + cc];
            fma4(a0, w0[mm], v);
            fma4(a1, w1[mm], v);
        }
        a0.x *= i0; a0.y *= i0; a0.z *= i0; a0.w *= i0;
        a1.x *= i1; a1.y *= i1; a1.z *= i1; a1.w *= i1;
        out[ti][0] = a0; out[ti][1] = a1;
    }
}

__global__ __launch_bounds__(320) void k_att(
    const float* __restrict__ qkv5,
    const float* __restrict__ A_s, const float* __restrict__ A_v,
    const float* __restrict__ adjS, const float* __restrict__ adjV,
    ushort_t* __restrict__ yhi, ushort_t* __restrict__ ylo)
{
    __shared__ __attribute__((aligned(16))) float sm[16184];
    float* aS  = sm;            // 4913  [n][j][k]
    float* aV  = sm + 4913;     // 4913  [j][n][m]
    float* ebS = sm + 9826;     // 289
    float* ebV = sm + 10115;    // 289
    float* buf = sm + 10404;    // 289*20

    const int t  = threadIdx.x;
    const int bh = blockIdx.x;
    const int b  = bh >> 3, h = bh & 7;
    const size_t rowbase = (size_t)b * 289;
    const int colq = h * 32;

    // q preload (all 8 quads) into registers
    float4 qreg[8];
    if (t < 289) {
        const float* qp = &qkv5[(rowbase + t) * 1280 + colq];
#pragma unroll
        for (int c = 0; c < 8; ++c) qreg[c] = *(const float4*)&qp[c * 4];
    }

    float4 pf[4];
    stage_load(qkv5, rowbase, 256 + colq + 0, t, pf);        // k-tile ch0 (even quads)

    // P0: exp of symmetrized biases
    for (int idx = t; idx < 578; idx += 320) {
        int f = idx / 289, rem = idx % 289;
        int jj = rem / 17, kk = rem % 17;
        float bias;
        if (f == 0)
            bias = 0.5f * ((A_s[jj*17+kk] + adjS[jj*17+kk]) + (A_s[kk*17+jj] + adjS[kk*17+jj]));
        else
            bias = 0.5f * ((A_v[jj*17+kk] + adjV[jj*17+kk]) + (A_v[kk*17+jj] + adjV[kk*17+jj]));
        (f ? ebV : ebS)[rem] = expf(bias);
    }

    stage_store(buf, t, pf);
    stage_load(qkv5, rowbase, 256 + colq + 4, t, pf);        // k-tile ch1 (odd quads)
    __syncthreads();

    // ---- scores ch0 ----
    float accS[17], accV[17];
#pragma unroll
    for (int i = 0; i < 17; ++i) { accS[i] = 0.f; accV[i] = 0.f; }
    const int a = t / 17, bb = t % 17;
    if (t < 289) {
        float4 qsel[4] = {qreg[0], qreg[2], qreg[4], qreg[6]};
        score_half(accS, accV, qsel, buf, a, bb);
    }
    __syncthreads();

    stage_store(buf, t, pf);
    stage_load(qkv5, rowbase, 1024 + colq + 0, t, pf);       // vsv ch0
    __syncthreads();

    // ---- scores ch1 + write raw scores ----
    if (t < 289) {
        float4 qsel[4] = {qreg[1], qreg[3], qreg[5], qreg[7]};
        score_half(accS, accV, qsel, buf, a, bb);
#pragma unroll
        for (int kk = 0; kk < 17; ++kk) aS[bb * 289 + a * 17 + kk] = accS[kk] * SCALE;
#pragma unroll
        for (int mm = 0; mm < 17; ++mm) aV[a * 289 + bb * 17 + mm] = accV[mm] * SCALE;
    }
    __syncthreads();

    // ---- softmax (in-place, unbiased) on all 578 rows ----
    for (int idx = t; idx < 578; idx += 320) {
        float* row = (idx < 289) ? &aS[idx * 17] : &aV[(idx - 289) * 17];
        float v[17];
#pragma unroll
        for (int kk = 0; kk < 17; ++kk) v[kk] = row[kk];
        float mx = v[0];
#pragma unroll
        for (int kk = 1; kk < 17; ++kk) mx = fmaxf(mx, v[kk]);
        float sum = 0.f;
#pragma unroll
        for (int kk = 0; kk < 17; ++kk) { v[kk] = expf(v[kk] - mx); sum += v[kk]; }
        float inv = 1.f / sum;
#pragma unroll
        for (int kk = 0; kk < 17; ++kk) row[kk] = v[kk] * inv;
    }
    __syncthreads();

    stage_store(buf, t, pf);                                 // buf = vsv ch0
    stage_load(qkv5, rowbase, 1024 + colq + 4, t, pf);       // vsv ch1
    __syncthreads();

    // ---- P3: x_vsv, 4 points/thread, ch0 then ch1 (acc held) ----
    const int c4 = (t & 3) * 4;       // buf slot offset
    const int q8 = (t & 3) * 8;       // output col base within 32-col section
    const int pb = (t >> 2) * 4;
    const int nv = (t < 292) ? ((289 - pb < 4) ? (289 - pb) : 4) : 0;
    int jj3[4], nn3[4];
    float eV[4][17];
    float4 acc3[2][4];
    if (t < 292) {
#pragma unroll
        for (int g = 0; g < 4; ++g) {
            int p = pb + g; if (p > 288) p = 288;
            jj3[g] = p / 17; nn3[g] = p % 17;
            const float* src = &aV[jj3[g] * 289 + nn3[g] * 17];
#pragma unroll
            for (int m = 0; m < 17; ++m) eV[g][m] = src[m];
        }
#pragma unroll
        for (int g = 0; g < 4; ++g) acc3[0][g] = (float4){0,0,0,0};
        for (int kk = 0; kk < 17; ++kk) {
            float4 tg[4];
#pragma unroll
            for (int g = 0; g < 4; ++g) tg[g] = (float4){0,0,0,0};
#pragma unroll
            for (int m = 0; m < 17; ++m) {
                float4 v = *(const float4*)&buf[(kk * 17 + m) * 20 + c4];
#pragma unroll
                for (int g = 0; g < 4; ++g) fma4(tg[g], eV[g][m], v);
            }
#pragma unroll
            for (int g = 0; g < 4; ++g)
                fma4(acc3[0][g], aS[nn3[g] * 289 + jj3[g] * 17 + kk], tg[g]);
        }
    }
    __syncthreads();

    stage_store(buf, t, pf);                                 // buf = vsv ch1
    stage_load(qkv5, rowbase, 512 + colq + 0, t, pf);        // vs ch0
    __syncthreads();

    if (t < 292) {
#pragma unroll
        for (int g = 0; g < 4; ++g) acc3[1][g] = (float4){0,0,0,0};
        for (int kk = 0; kk < 17; ++kk) {
            float4 tg[4];
#pragma unroll
            for (int g = 0; g < 4; ++g) tg[g] = (float4){0,0,0,0};
#pragma unroll
            for (int m = 0; m < 17; ++m) {
                float4 v = *(const float4*)&buf[(kk * 17 + m) * 20 + c4];
#pragma unroll
                for (int g = 0; g < 4; ++g) fma4(tg[g], eV[g][m], v);
            }
#pragma unroll
            for (int g = 0; g < 4; ++g)
                fma4(acc3[1][g], aS[nn3[g] * 289 + jj3[g] * 17 + kk], tg[g]);
        }
        for (int g = 0; g < nv; ++g) {
            size_t base = (rowbase + pb + g) * 768 + colq + q8;
            store_hilo8(yhi, ylo, base, acc3[0][g], acc3[1][g]);
        }
    }
    __syncthreads();

    stage_store(buf, t, pf);                                 // buf = vs ch0
    stage_load(qkv5, rowbase, 512 + colq + 4, t, pf);        // vs ch1
    __syncthreads();

    // ---- P4: x_vs, ch0 (held) then ch1 + combined 16B store ----
    float4 hold[2][2][2];   // [ch][ti][row]
    p4_round(aS, ebS, buf, t, hold[0]);
    __syncthreads();

    stage_store(buf, t, pf);                                 // buf = vs ch1
    stage_load(qkv5, rowbase, 768 + colq + 0, t, pf);        // vv ch0
    __syncthreads();

    p4_round(aS, ebS, buf, t, hold[1]);
#pragma unroll
    for (int ti = 0; ti < 2; ++ti) {
        int u = t + ti * 320;
        if (u >= 612) break;
        int qq8 = (u & 3) * 8, rest = u >> 2;
        int n = rest % 17, jp = rest / 17;
        int j0 = jp * 2;
        size_t base0 = (rowbase + j0 * 17 + n) * 768 + 256 + colq + qq8;
        store_hilo8(yhi, ylo, base0, hold[0][ti][0], hold[1][ti][0]);
        if (j0 != 16) {
            size_t base1 = (rowbase + (j0 + 1) * 17 + n) * 768 + 256 + colq + qq8;
            store_hilo8(yhi, ylo, base1, hold[0][ti][1], hold[1][ti][1]);
        }
    }
    __syncthreads();

    stage_store(buf, t, pf);                                 // buf = vv ch0
    stage_load(qkv5, rowbase, 768 + colq + 4, t, pf);        // vv ch1
    __syncthreads();

    // ---- P5: x_vv, ch0 (held) then ch1 + combined 16B store ----
    p5_round(aV, ebV, buf, t, hold[0]);
    __syncthreads();

    stage_store(buf, t, pf);                                 // buf = vv ch1
    __syncthreads();

    p5_round(aV, ebV, buf, t, hold[1]);
#pragma unroll
    for (int ti = 0; ti < 2; ++ti) {
        int u = t + ti * 320;
        if (u >= 612) break;
        int qq8 = (u & 3) * 8, rest = u >> 2;
        int j = rest % 17, np = rest / 17;
        int n0 = np * 2;
        size_t base0 = (rowbase + j * 17 + n0) * 768 + 512 + colq + qq8;
        store_hilo8(yhi, ylo, base0, hold[0][ti][0], hold[1][ti][0]);
        if (n0 != 16) {
            size_t base1 = (rowbase + j * 17 + n0 + 1) * 768 + 512 + colq + qq8;
            store_hilo8(yhi, ylo, base1, hold[0][ti][1], hold[1][ti][1]);
        }
    }
}

extern "C" void kernel_launch(void* const* d_in, const int* in_sizes, int n_in,
                              void* d_out, int out_size, void* d_ws, size_t ws_size,
                              hipStream_t stream)
{
    const float* x    = (const float*)d_in[0];
    const float* A_s  = (const float*)d_in[1];
    const float* A_v  = (const float*)d_in[2];
    const float* Wqkv = (const float*)d_in[3];
    const float* Wp   = (const float*)d_in[4];
    const float* bp   = (const float*)d_in[5];
    const float* M    = (const float*)d_in[6];
    const float* adjS = (const float*)d_in[7];
    const float* adjV = (const float*)d_in[8];
    float* out = (float*)d_out;

    char* w = (char*)d_ws;
    float*    qkv5  = (float*)w;                          // 95 MB, dead after k_att
    ushort_t* wph   = (ushort_t*)w;                       // written after k_att
    ushort_t* wpl   = (ushort_t*)(w + 393216);
    char* R = w + 134946816;
    ushort_t* xhi = (ushort_t*)R;
    ushort_t* xlo = (ushort_t*)(R + 9469952);
    ushort_t* wqh = (ushort_t*)(R + 18939904);
    ushort_t* wql = (ushort_t*)(R + 19595264);
    ushort_t* yhi = (ushort_t*)R;                         // alias (after qkv gemm done)
    ushort_t* ylo = (ushort_t*)(R + 28422144);

    k_cvt_xw<<<dim3(5904), 256, 0, stream>>>((const float4*)x, (ushort4*)xhi, (ushort4*)xlo,
                                             Wqkv, wqh, wql);
    k_gemm<128, 128, 256, 0><<<dim3(10, 145), 256, 0, stream>>>(xhi, xlo, wqh, wql, M, qkv5);
    k_att<<<dim3(512), 320, 0, stream>>>(qkv5, A_s, A_v, adjS, adjV, yhi, ylo);
    k_cvt_wp<<<dim3(256), 256, 0, stream>>>(Wp, wph, wpl);
    k_gemm<128, 64, 768, 1><<<dim3(4, 145), 256, 0, stream>>>(yhi, ylo, wph, wpl, bp, out);
}

// Round 9
// 340.277 us; speedup vs baseline: 1.0616x; 1.0153x over previous
//
#include <hip/hip_runtime.h>
#include <math.h>

#define ROWS 18496          // bt*J*N = 64*17*17
#define SCALE 0.17677669529663687f  // 1/sqrt(32)

typedef unsigned short ushort_t;
typedef __attribute__((ext_vector_type(8))) short short8;
typedef __attribute__((ext_vector_type(8))) unsigned short us8;
typedef __attribute__((ext_vector_type(4))) float f32x4;

__device__ __forceinline__ void fma4(float4& d, float s, const float4& v) {
    d.x = fmaf(s, v.x, d.x); d.y = fmaf(s, v.y, d.y);
    d.z = fmaf(s, v.z, d.z); d.w = fmaf(s, v.w, d.w);
}
__device__ __forceinline__ float dot4(const float4& a, const float4& b) {
    return a.x*b.x + a.y*b.y + a.z*b.z + a.w*b.w;
}

__device__ __forceinline__ ushort_t f2bf(float x) {
    union { float f; unsigned u; } v; v.f = x;
    unsigned r = v.u + 0x7fffu + ((v.u >> 16) & 1u);
    return (ushort_t)(r >> 16);
}
__device__ __forceinline__ float bf2f(ushort_t b) {
    union { unsigned u; float f; } v; v.u = ((unsigned)b) << 16; return v.f;
}

__device__ __forceinline__ void gl_lds16(const void* g, void* l) {
    __builtin_amdgcn_global_load_lds(
        (const __attribute__((address_space(1))) void*)g,
        (__attribute__((address_space(3))) void*)l, 16, 0, 0);
}

// y2 layout: [row][1536] ushorts = [row][chunk=h*3+sec][hi:32|lo:32].
// Block (b,h) writes 3 fully-owned 128B lines per row -> no cross-XCD sharing.
__device__ __forceinline__ void store_y2(ushort_t* __restrict__ y2,
    size_t row, int chunk, int q8, const float4& a0, const float4& a1)
{
    us8 h, l;
    h[0] = f2bf(a0.x); l[0] = f2bf(a0.x - bf2f(h[0]));
    h[1] = f2bf(a0.y); l[1] = f2bf(a0.y - bf2f(h[1]));
    h[2] = f2bf(a0.z); l[2] = f2bf(a0.z - bf2f(h[2]));
    h[3] = f2bf(a0.w); l[3] = f2bf(a0.w - bf2f(h[3]));
    h[4] = f2bf(a1.x); l[4] = f2bf(a1.x - bf2f(h[4]));
    h[5] = f2bf(a1.y); l[5] = f2bf(a1.y - bf2f(h[5]));
    h[6] = f2bf(a1.z); l[6] = f2bf(a1.z - bf2f(h[6]));
    h[7] = f2bf(a1.w); l[7] = f2bf(a1.w - bf2f(h[7]));
    size_t off = row * 1536 + chunk * 64 + q8;
    *(us8*)&y2[off]      = h;
    *(us8*)&y2[off + 32] = l;
}

// ---------------- merged conversion kernel ----------------------------
__global__ __launch_bounds__(256) void k_cvt_xw(
    const float4* __restrict__ x, ushort4* __restrict__ xhi, ushort4* __restrict__ xlo,
    const float* __restrict__ W, ushort_t* __restrict__ bh, ushort_t* __restrict__ bl)
{
    if (blockIdx.x < 4624) {
        int i = blockIdx.x * 256 + threadIdx.x;
        float4 v = x[i];
        ushort4 h, l;
        h.x = f2bf(v.x); l.x = f2bf(v.x - bf2f(h.x));
        h.y = f2bf(v.y); l.y = f2bf(v.y - bf2f(h.y));
        h.z = f2bf(v.z); l.z = f2bf(v.z - bf2f(h.z));
        h.w = f2bf(v.w); l.w = f2bf(v.w - bf2f(h.w));
        xhi[i] = h; xlo[i] = l;
    } else {
        int o = blockIdx.x - 4624;   // 0..1279
        int kk = threadIdx.x;        // 0..255
        int col = (o & 255) * 5 + (o >> 8);
        float v = W[(size_t)kk * 1280 + col];
        ushort_t hh = f2bf(v);
        bh[(size_t)o * 256 + kk] = hh;
        bl[(size_t)o * 256 + kk] = f2bf(v - bf2f(hh));
    }
}

// Wp (768x256 f32) -> transposed bf16 [n][k_eff], k_eff permuted to match
// the y2 interleaved A layout: j=k/32, h=j/3, sec=j%3, cc=k%32,
// k_orig = sec*256 + h*32 + cc.
__global__ __launch_bounds__(256) void k_cvt_wp(
    const float* __restrict__ W, ushort_t* __restrict__ bh, ushort_t* __restrict__ bl)
{
    int n = blockIdx.x;          // 0..255
    for (int k = threadIdx.x; k < 768; k += 256) {
        int j = k >> 5, cc = k & 31;
        int h = j / 3, sec = j % 3;
        int ko = sec * 256 + h * 32 + cc;
        float v = W[(size_t)ko * 256 + n];
        ushort_t hh = f2bf(v);
        bh[(size_t)n * 768 + k] = hh;
        bl[(size_t)n * 768 + k] = f2bf(v - bf2f(hh));
    }
}

// ---------------- split-bf16 MFMA GEMM --------------------------------
// AI=0: Ahi/Alo planar [row][K]. AI=1: Ahi = y2 interleaved [row][K/32][hi32|lo32].
template<int BM, int BN, int K, int MODE, int AI>
__global__ __launch_bounds__(256) void k_gemm(
    const ushort_t* __restrict__ Ahi, const ushort_t* __restrict__ Alo,
    const ushort_t* __restrict__ Bhi, const ushort_t* __restrict__ Blo,
    const float* __restrict__ aux,
    float* __restrict__ out)
{
    constexpr int MT = BM / 32;
    constexpr int NT = BN / 32;
    __shared__ __attribute__((aligned(16))) ushort_t sAh[BM * 32];
    __shared__ __attribute__((aligned(16))) ushort_t sAl[BM * 32];
    __shared__ __attribute__((aligned(16))) ushort_t sBh[BN * 32];
    __shared__ __attribute__((aligned(16))) ushort_t sBl[BN * 32];

    const int t = threadIdx.x;
    const int lane = t & 63;
    const int ln = lane & 15, quad = lane >> 4;
    const int wave = t >> 6;
    const int wm = wave >> 1, wn = wave & 1;
    const int m0 = blockIdx.y * BM, n0 = blockIdx.x * BN;

    f32x4 acc[MT][NT];
#pragma unroll
    for (int i = 0; i < MT; ++i)
#pragma unroll
        for (int j = 0; j < NT; ++j) acc[i][j] = (f32x4){0.f, 0.f, 0.f, 0.f};

    for (int kb = 0; kb < K; kb += 32) {
        __syncthreads();
#pragma unroll
        for (int s = t; s < BM * 4; s += 256) {
            int row = s >> 2, kc = s & 3;
            int gr = m0 + row; if (gr > ROWS - 1) gr = ROWS - 1;
            int lb = (s & ~63) * 16;
            if (AI) {
                size_t gb = (size_t)gr * 3072 + (kb >> 5) * 128 + kc * 16;
                gl_lds16((const char*)Ahi + gb,      (char*)sAh + lb);
                gl_lds16((const char*)Ahi + gb + 64, (char*)sAl + lb);
            } else {
                size_t gb = ((size_t)gr * K + kb) * 2 + kc * 16;
                gl_lds16((const char*)Ahi + gb, (char*)sAh + lb);
                gl_lds16((const char*)Alo + gb, (char*)sAl + lb);
            }
        }
#pragma unroll
        for (int s = t; s < BN * 4; s += 256) {
            int row = s >> 2, kc = s & 3;
            size_t gb = ((size_t)(n0 + row) * K + kb) * 2 + kc * 16;
            int lb = (s & ~63) * 16;
            gl_lds16((const char*)Bhi + gb, (char*)sBh + lb);
            gl_lds16((const char*)Blo + gb, (char*)sBl + lb);
        }
        __syncthreads();

        short8 ah[MT], al[MT], bh[NT], bl[NT];
#pragma unroll
        for (int i = 0; i < MT; ++i) {
            int off = (wm * (BM / 2) + i * 16 + ln) * 32 + quad * 8;
            ah[i] = *(const short8*)&sAh[off];
            al[i] = *(const short8*)&sAl[off];
        }
#pragma unroll
        for (int j = 0; j < NT; ++j) {
            int off = (wn * (BN / 2) + j * 16 + ln) * 32 + quad * 8;
            bh[j] = *(const short8*)&sBh[off];
            bl[j] = *(const short8*)&sBl[off];
        }
#pragma unroll
        for (int i = 0; i < MT; ++i)
#pragma unroll
            for (int j = 0; j < NT; ++j) {
                acc[i][j] = __builtin_amdgcn_mfma_f32_16x16x32_bf16(ah[i], bh[j], acc[i][j], 0, 0, 0);
                acc[i][j] = __builtin_amdgcn_mfma_f32_16x16x32_bf16(ah[i], bl[j], acc[i][j], 0, 0, 0);
                acc[i][j] = __builtin_amdgcn_mfma_f32_16x16x32_bf16(al[i], bh[j], acc[i][j], 0, 0, 0);
            }
    }

#pragma unroll
    for (int i = 0; i < MT; ++i) {
#pragma unroll
        for (int r = 0; r < 4; ++r) {
            int gm = m0 + wm * (BM / 2) + i * 16 + quad * 4 + r;
            if (gm >= ROWS) continue;
            if (MODE == 0) {
                int jn = gm % 289;
                const float* Mrow = &aux[(size_t)jn * 256];
#pragma unroll
                for (int j = 0; j < NT; ++j) {
                    int gn = n0 + wn * (BN / 2) + j * 16 + ln;
                    out[(size_t)gm * 1280 + gn] = acc[i][j][r] * Mrow[gn & 255];
                }
            } else {
#pragma unroll
                for (int j = 0; j < NT; ++j) {
                    int gn = n0 + wn * (BN / 2) + j * 16 + ln;
                    out[(size_t)gm * 256 + gn] = acc[i][j][r] + aux[gn];
                }
            }
        }
    }
}

// ---------------- fused attention v5 -----------------------------------
// As R8 (reg-prefetch pipeline, interleaved col-quads ch0=even/ch1=odd) but
// stores go to the line-owned y2 layout.
__device__ __forceinline__ void stage_load(const float* __restrict__ qkv5,
    size_t rowbase, int colbase, int t, float4* pf)
{
#pragma unroll
    for (int r = 0; r < 4; ++r) {
        int idx = t + r * 320;
        if (idx < 1156) {
            int p = idx >> 2, c = idx & 3;
            pf[r] = *(const float4*)&qkv5[(rowbase + p) * 1280 + colbase + c * 8];
        }
    }
}
__device__ __forceinline__ void stage_store(float* buf, int t, const float4* pf)
{
#pragma unroll
    for (int r = 0; r < 4; ++r) {
        int idx = t + r * 320;
        if (idx < 1156) {
            int p = idx >> 2, c = idx & 3;
            *(float4*)&buf[p * 20 + c * 4] = pf[r];
        }
    }
}

__device__ __forceinline__ void score_half(
    float* accS, float* accV, const float4* qsel, const float* buf, int a, int bb)
{
#pragma unroll
    for (int kk = 0; kk < 17; ++kk) {
        const float4* r = (const float4*)&buf[(kk * 17 + bb) * 20];
        accS[kk] += dot4(qsel[0], r[0]) + dot4(qsel[1], r[1]) + dot4(qsel[2], r[2]) + dot4(qsel[3], r[3]);
    }
#pragma unroll
    for (int mm = 0; mm < 17; ++mm) {
        const float4* r = (const float4*)&buf[(a * 17 + mm) * 20];
        accV[mm] += dot4(qsel[0], r[0]) + dot4(qsel[1], r[1]) + dot4(qsel[2], r[2]) + dot4(qsel[3], r[3]);
    }
}

__device__ __forceinline__ void p4_round(
    const float* aS, const float* ebS, const float* buf, int t, float4 out[2][2])
{
#pragma unroll
    for (int ti = 0; ti < 2; ++ti) {
        int u = t + ti * 320;
        if (u >= 612) break;
        int cc = (u & 3) * 4, rest = u >> 2;
        int n = rest % 17, jp = rest / 17;
        int j0 = jp * 2;
        int j1 = (j0 + 1 > 16) ? 16 : j0 + 1;
        float w0[17], w1[17];
        float s0 = 0.f, s1 = 0.f;
        const float* as0 = &aS[n * 289 + j0 * 17];
        const float* as1 = &aS[n * 289 + j1 * 17];
        const float* e0 = &ebS[j0 * 17];
        const float* e1 = &ebS[j1 * 17];
#pragma unroll
        for (int kk = 0; kk < 17; ++kk) {
            w0[kk] = as0[kk] * e0[kk]; s0 += w0[kk];
            w1[kk] = as1[kk] * e1[kk]; s1 += w1[kk];
        }
        float i0 = 1.f / s0, i1 = 1.f / s1;
        float4 a0 = {0,0,0,0}, a1 = {0,0,0,0};
        for (int kk = 0; kk < 17; ++kk) {
            float4 v = *(const float4*)&buf[(kk * 17 + n) * 20 + cc];
            fma4(a0, w0[kk], v);
            fma4(a1, w1[kk], v);
        }
        a0.x *= i0; a0.y *= i0; a0.z *= i0; a0.w *= i0;
        a1.x *= i1; a1.y *= i1; a1.z *= i1; a1.w *= i1;
        out[ti][0] = a0; out[ti][1] = a1;
    }
}

__device__ __forceinline__ void p5_round(
    const float* aV, const float* ebV, const float* buf, int t, float4 out[2][2])
{
#pragma unroll
    for (int ti = 0; ti < 2; ++ti) {
        int u = t + ti * 320;
        if (u >= 612) break;
        int cc = (u & 3) * 4, rest = u >> 2;
        int j = rest % 17, np = rest / 17;
        int n0 = np * 2;
        int n1 = (n0 + 1 > 16) ? 16 : n0 + 1;
        float w0[17], w1[17];
        float s0 = 0.f, s1 = 0.f;
        const float* av0 = &aV[j * 289 + n0 * 17];
        const float* av1 = &aV[j * 289 + n1 * 17];
        const float* e0 = &ebV[n0 * 17];
        const float* e1 = &ebV[n1 * 17];
#pragma unroll
        for (int mm = 0; mm < 17; ++mm) {
            w0[mm] = av0[mm] * e0[mm]; s0 += w0[mm];
            w1[mm] = av1[mm] * e1[mm]; s1 += w1[mm];
        }
        float i0 = 1.f / s0, i1 = 1.f / s1;
        float4 a0 = {0,0,0,0}, a1 = {0,0,0,0};
        for (int mm = 0; mm < 17; ++mm) {
            float4 v = *(const float4*)&buf[(j * 17 + mm) * 20 + cc];
            fma4(a0, w0[mm], v);
            fma4(a1, w1[mm], v);
        }
        a0.x *= i0; a0.y *= i0; a0.z *= i0; a0.w *= i0;
        a1.x *= i1; a1.y *= i1; a1.z *= i1; a1.w *= i1;
        out[ti][0] = a0; out[ti][1] = a1;
    }
}

__global__ __launch_bounds__(320) void k_att(
    const float* __restrict__ qkv5,
    const float* __restrict__ A_s, const float* __restrict__ A_v,
    const float* __restrict__ adjS, const float* __restrict__ adjV,
    ushort_t* __restrict__ y2)
{
    __shared__ __attribute__((aligned(16))) float sm[16184];
    float* aS  = sm;            // 4913  [n][j][k]
    float* aV  = sm + 4913;     // 4913  [j][n][m]
    float* ebS = sm + 9826;     // 289
    float* ebV = sm + 10115;    // 289
    float* buf = sm + 10404;    // 289*20

    const int t  = threadIdx.x;
    const int bh = blockIdx.x;
    const int b  = bh >> 3, h = bh & 7;
    const size_t rowbase = (size_t)b * 289;
    const int colq = h * 32;
    const int ch0 = h * 3;      // y2 chunk for sec 0

    // q preload (all 8 quads) into registers
    float4 qreg[8];
    if (t < 289) {
        const float* qp = &qkv5[(rowbase + t) * 1280 + colq];
#pragma unroll
        for (int c = 0; c < 8; ++c) qreg[c] = *(const float4*)&qp[c * 4];
    }

    float4 pf[4];
    stage_load(qkv5, rowbase, 256 + colq + 0, t, pf);        // k-tile ch0 (even quads)

    // P0: exp of symmetrized biases
    for (int idx = t; idx < 578; idx += 320) {
        int f = idx / 289, rem = idx % 289;
        int jj = rem / 17, kk = rem % 17;
        float bias;
        if (f == 0)
            bias = 0.5f * ((A_s[jj*17+kk] + adjS[jj*17+kk]) + (A_s[kk*17+jj] + adjS[kk*17+jj]));
        else
            bias = 0.5f * ((A_v[jj*17+kk] + adjV[jj*17+kk]) + (A_v[kk*17+jj] + adjV[kk*17+jj]));
        (f ? ebV : ebS)[rem] = expf(bias);
    }

    stage_store(buf, t, pf);
    stage_load(qkv5, rowbase, 256 + colq + 4, t, pf);        // k-tile ch1 (odd quads)
    __syncthreads();

    // ---- scores ch0 ----
    float accS[17], accV[17];
#pragma unroll
    for (int i = 0; i < 17; ++i) { accS[i] = 0.f; accV[i] = 0.f; }
    const int a = t / 17, bb = t % 17;
    if (t < 289) {
        float4 qsel[4] = {qreg[0], qreg[2], qreg[4], qreg[6]};
        score_half(accS, accV, qsel, buf, a, bb);
    }
    __syncthreads();

    stage_store(buf, t, pf);
    stage_load(qkv5, rowbase, 1024 + colq + 0, t, pf);       // vsv ch0
    __syncthreads();

    // ---- scores ch1 + write raw scores ----
    if (t < 289) {
        float4 qsel[4] = {qreg[1], qreg[3], qreg[5], qreg[7]};
        score_half(accS, accV, qsel, buf, a, bb);
#pragma unroll
        for (int kk = 0; kk < 17; ++kk) aS[bb * 289 + a * 17 + kk] = accS[kk] * SCALE;
#pragma unroll
        for (int mm = 0; mm < 17; ++mm) aV[a * 289 + bb * 17 + mm] = accV[mm] * SCALE;
    }
    __syncthreads();

    // ---- softmax (in-place, unbiased) on all 578 rows ----
    for (int idx = t; idx < 578; idx += 320) {
        float* row = (idx < 289) ? &aS[idx * 17] : &aV[(idx - 289) * 17];
        float v[17];
#pragma unroll
        for (int kk = 0; kk < 17; ++kk) v[kk] = row[kk];
        float mx = v[0];
#pragma unroll
        for (int kk = 1; kk < 17; ++kk) mx = fmaxf(mx, v[kk]);
        float sum = 0.f;
#pragma unroll
        for (int kk = 0; kk < 17; ++kk) { v[kk] = expf(v[kk] - mx); sum += v[kk]; }
        float inv = 1.f / sum;
#pragma unroll
        for (int kk = 0; kk < 17; ++kk) row[kk] = v[kk] * inv;
    }
    __syncthreads();

    stage_store(buf, t, pf);                                 // buf = vsv ch0
    stage_load(qkv5, rowbase, 1024 + colq + 4, t, pf);       // vsv ch1
    __syncthreads();

    // ---- P3: x_vsv, 4 points/thread, ch0 then ch1 (acc held) ----
    const int c4 = (t & 3) * 4;       // buf slot offset
    const int q8 = (t & 3) * 8;       // output col base within 64-ushort chunk
    const int pb = (t >> 2) * 4;
    const int nv = (t < 292) ? ((289 - pb < 4) ? (289 - pb) : 4) : 0;
    int jj3[4], nn3[4];
    float eV[4][17];
    float4 acc3[2][4];
    if (t < 292) {
#pragma unroll
        for (int g = 0; g < 4; ++g) {
            int p = pb + g; if (p > 288) p = 288;
            jj3[g] = p / 17; nn3[g] = p % 17;
            const float* src = &aV[jj3[g] * 289 + nn3[g] * 17];
#pragma unroll
            for (int m = 0; m < 17; ++m) eV[g][m] = src[m];
        }
#pragma unroll
        for (int g = 0; g < 4; ++g) acc3[0][g] = (float4){0,0,0,0};
        for (int kk = 0; kk < 17; ++kk) {
            float4 tg[4];
#pragma unroll
            for (int g = 0; g < 4; ++g) tg[g] = (float4){0,0,0,0};
#pragma unroll
            for (int m = 0; m < 17; ++m) {
                float4 v = *(const float4*)&buf[(kk * 17 + m) * 20 + c4];
#pragma unroll
                for (int g = 0; g < 4; ++g) fma4(tg[g], eV[g][m], v);
            }
#pragma unroll
            for (int g = 0; g < 4; ++g)
                fma4(acc3[0][g], aS[nn3[g] * 289 + jj3[g] * 17 + kk], tg[g]);
        }
    }
    __syncthreads();

    stage_store(buf, t, pf);                                 // buf = vsv ch1
    stage_load(qkv5, rowbase, 512 + colq + 0, t, pf);        // vs ch0
    __syncthreads();

    if (t < 292) {
#pragma unroll
        for (int g = 0; g < 4; ++g) acc3[1][g] = (float4){0,0,0,0};
        for (int kk = 0; kk < 17; ++kk) {
            float4 tg[4];
#pragma unroll
            for (int g = 0; g < 4; ++g) tg[g] = (float4){0,0,0,0};
#pragma unroll
            for (int m = 0; m < 17; ++m) {
                float4 v = *(const float4*)&buf[(kk * 17 + m) * 20 + c4];
#pragma unroll
                for (int g = 0; g < 4; ++g) fma4(tg[g], eV[g][m], v);
            }
#pragma unroll
            for (int g = 0; g < 4; ++g)
                fma4(acc3[1][g], aS[nn3[g] * 289 + jj3[g] * 17 + kk], tg[g]);
        }
        for (int g = 0; g < nv; ++g)
            store_y2(y2, rowbase + pb + g, ch0 + 0, q8, acc3[0][g], acc3[1][g]);
    }
    __syncthreads();

    stage_store(buf, t, pf);                                 // buf = vs ch0
    stage_load(qkv5, rowbase, 512 + colq + 4, t, pf);        // vs ch1
    __syncthreads();

    // ---- P4: x_vs, ch0 (held) then ch1 + combined store ----
    float4 hold[2][2][2];   // [ch][ti][row]
    p4_round(aS, ebS, buf, t, hold[0]);
    __syncthreads();

    stage_store(buf, t, pf);                                 // buf = vs ch1
    stage_load(qkv5, rowbase, 768 + colq + 0, t, pf);        // vv ch0
    __syncthreads();

    p4_round(aS, ebS, buf, t, hold[1]);
#pragma unroll
    for (int ti = 0; ti < 2; ++ti) {
        int u = t + ti * 320;
        if (u >= 612) break;
        int qq8 = (u & 3) * 8, rest = u >> 2;
        int n = rest % 17, jp = rest / 17;
        int j0 = jp * 2;
        store_y2(y2, rowbase + j0 * 17 + n, ch0 + 1, qq8, hold[0][ti][0], hold[1][ti][0]);
        if (j0 != 16)
            store_y2(y2, rowbase + (j0 + 1) * 17 + n, ch0 + 1, qq8, hold[0][ti][1], hold[1][ti][1]);
    }
    __syncthreads();

    stage_store(buf, t, pf);                                 // buf = vv ch0
    stage_load(qkv5, rowbase, 768 + colq + 4, t, pf);        // vv ch1
    __syncthreads();

    // ---- P5: x_vv, ch0 (held) then ch1 + combined store ----
    p5_round(aV, ebV, buf, t, hold[0]);
    __syncthreads();

    stage_store(buf, t, pf);                                 // buf = vv ch1
    __syncthreads();

    p5_round(aV, ebV, buf, t, hold[1]);
#pragma unroll
    for (int ti = 0; ti < 2; ++ti) {
        int u = t + ti * 320;
        if (u >= 612) break;
        int qq8 = (u & 3) * 8, rest = u >> 2;
        int j = rest % 17, np = rest / 17;
        int n0 = np * 2;
        store_y2(y2, rowbase + j * 17 + n0, ch0 + 2, qq8, hold[0][ti][0], hold[1][ti][0]);
        if (n0 != 16)
            store_y2(y2, rowbase + j * 17 + n0 + 1, ch0 + 2, qq8, hold[0][ti][1], hold[1][ti][1]);
    }
}

extern "C" void kernel_launch(void* const* d_in, const int* in_sizes, int n_in,
                              void* d_out, int out_size, void* d_ws, size_t ws_size,
                              hipStream_t stream)
{
    const float* x    = (const float*)d_in[0];
    const float* A_s  = (const float*)d_in[1];
    const float* A_v  = (const float*)d_in[2];
    const float* Wqkv = (const float*)d_in[3];
    const float* Wp   = (const float*)d_in[4];
    const float* bp   = (const float*)d_in[5];
    const float* M    = (const float*)d_in[6];
    const float* adjS = (const float*)d_in[7];
    const float* adjV = (const float*)d_in[8];
    float* out = (float*)d_out;

    char* w = (char*)d_ws;
    float*    qkv5  = (float*)w;                          // 95 MB, dead after k_att
    ushort_t* wph   = (ushort_t*)w;                       // written after k_att
    ushort_t* wpl   = (ushort_t*)(w + 393216);
    char* R = w + 134946816;
    ushort_t* xhi = (ushort_t*)R;
    ushort_t* xlo = (ushort_t*)(R + 9469952);
    ushort_t* wqh = (ushort_t*)(R + 18939904);
    ushort_t* wql = (ushort_t*)(R + 19595264);
    ushort_t* y2  = (ushort_t*)R;   // 18496*1536*2 B = 56.8 MB (after qkv gemm done)

    k_cvt_xw<<<dim3(5904), 256, 0, stream>>>((const float4*)x, (ushort4*)xhi, (ushort4*)xlo,
                                             Wqkv, wqh, wql);
    k_gemm<128, 128, 256, 0, 0><<<dim3(10, 145), 256, 0, stream>>>(xhi, xlo, wqh, wql, M, qkv5);
    k_att<<<dim3(512), 320, 0, stream>>>(qkv5, A_s, A_v, adjS, adjV, y2);
    k_cvt_wp<<<dim3(256), 256, 0, stream>>>(Wp, wph, wpl);
    k_gemm<128, 64, 768, 1, 1><<<dim3(4, 145), 256, 0, stream>>>(y2, y2, wph, wpl, bp, out);
}